// Round 1
// baseline (230.726 us; speedup 1.0000x reference)
//
#include <hip/hip_runtime.h>

// AtomDistances: B=16, A=4096, N=128
//   out[b,a,n] = mask[b,a,n] ? || pos[b,nbr[b,a,n]] - pos[b,a] + co[b,a,n,:] @ cell[b] || : 0
//
// Memory-bound elementwise-with-gather. One thread handles 4 consecutive n's:
//   neighbors/mask as int4, cell_offsets as 3x float4 (48B aligned), out as float4.
// b is uniform per block (1024 elems/block, A*N=524288 divisible) -> scalar cell loads.

#define A_DIM 4096
#define N_DIM 128

__global__ __launch_bounds__(256) void atom_distances_kernel(
    const float* __restrict__ positions,     // (B, A, 3)
    const int*   __restrict__ neighbors,     // (B, A, N) int32
    const float* __restrict__ cell,          // (B, 3, 3)
    const float* __restrict__ cell_offsets,  // (B, A, N, 3)
    const int*   __restrict__ mask,          // (B, A, N) int32 (0/1)
    float* __restrict__ out)                 // (B, A, N)
{
    const int ELEMS_PER_BLOCK = 1024;                          // 256 threads * 4 elems
    const int BLOCKS_PER_BATCH = (A_DIM * N_DIM) / ELEMS_PER_BLOCK; // 512

    const int b = blockIdx.x / BLOCKS_PER_BATCH;               // block-uniform
    const int r = (blockIdx.x % BLOCKS_PER_BATCH) * ELEMS_PER_BLOCK + threadIdx.x * 4;
    const int a = r >> 7;                                      // r / N_DIM
    const int e = b * (A_DIM * N_DIM) + r;                     // flat element base (fits int32)

    // cell for this batch — b is wave-uniform, these become scalar loads
    const float* cb = cell + b * 9;
    const float c00 = cb[0], c01 = cb[1], c02 = cb[2];
    const float c10 = cb[3], c11 = cb[4], c12 = cb[5];
    const float c20 = cb[6], c21 = cb[7], c22 = cb[8];

    const float* pb = positions + b * (A_DIM * 3);
    const float ax = pb[a * 3 + 0];
    const float ay = pb[a * 3 + 1];
    const float az = pb[a * 3 + 2];

    // streaming loads, 16 B/lane
    const int4 nb = *(const int4*)(neighbors + e);
    const int4 mk = *(const int4*)(mask + e);
    const float4* co = (const float4*)(cell_offsets + (size_t)e * 3);
    const float4 o0 = co[0];
    const float4 o1 = co[1];
    const float4 o2 = co[2];

    float cox[4], coy[4], coz[4];
    cox[0] = o0.x; coy[0] = o0.y; coz[0] = o0.z;
    cox[1] = o0.w; coy[1] = o1.x; coz[1] = o1.y;
    cox[2] = o1.z; coy[2] = o1.w; coz[2] = o2.x;
    cox[3] = o2.y; coy[3] = o2.z; coz[3] = o2.w;

    const int jj[4] = { nb.x, nb.y, nb.z, nb.w };
    const int mm[4] = { mk.x, mk.y, mk.z, mk.w };

    float res[4];
#pragma unroll
    for (int k = 0; k < 4; ++k) {
        const float* pj = pb + jj[k] * 3;   // gather: 48 KB window per batch, L1/L2-resident
        const float px = pj[0];
        const float py = pj[1];
        const float pz = pj[2];
        const float dx = px - ax + cox[k] * c00 + coy[k] * c10 + coz[k] * c20;
        const float dy = py - ay + cox[k] * c01 + coy[k] * c11 + coz[k] * c21;
        const float dz = pz - az + cox[k] * c02 + coy[k] * c12 + coz[k] * c22;
        const float d = sqrtf(dx * dx + dy * dy + dz * dz);
        res[k] = mm[k] ? d : 0.0f;
    }

    *(float4*)(out + e) = make_float4(res[0], res[1], res[2], res[3]);
}

extern "C" void kernel_launch(void* const* d_in, const int* in_sizes, int n_in,
                              void* d_out, int out_size, void* d_ws, size_t ws_size,
                              hipStream_t stream) {
    const float* positions    = (const float*)d_in[0];
    const int*   neighbors    = (const int*)d_in[1];
    const float* cell         = (const float*)d_in[2];
    const float* cell_offsets = (const float*)d_in[3];
    const int*   mask         = (const int*)d_in[4];
    float* out = (float*)d_out;

    const int total = out_size;                 // B*A*N = 8,388,608
    const int blocks = total / 1024;            // 8192
    atom_distances_kernel<<<blocks, 256, 0, stream>>>(
        positions, neighbors, cell, cell_offsets, mask, out);
}